// Round 2
// baseline (201.365 us; speedup 1.0000x reference)
//
#include <hip/hip_runtime.h>

// Problem constants (from reference)
#define KSIZE   32
#define KSTRIDE 16
#define HK      4
#define HD      128
#define ROW     (HK * HD)                       // 512 floats per token
#define ROW4    (ROW / 4)                       // 128 float4 per token
#define BATCH   4
#define SEQLEN  16384
#define CHUNKS_PER_BATCH ((SEQLEN - KSIZE) / KSTRIDE + 1)   // 1023
#define TOTAL_CHUNKS     (BATCH * CHUNKS_PER_BATCH)         // 4092
#define NXCD 8

// One chunk per 128-thread block. 4092 blocks * 2 waves = 32 waves/CU (full
// residency) vs 10.7 for the G=3 grouping — this kernel is cold-HBM
// latency-bound, and TLP is the lever. The nominal 2x read amplification
// (adjacent chunks share a 16-row half-window) is absorbed by L2 (same-XCD
// via swizzle, 32KB/boundary vs 4MiB L2) or at worst the die-shared 256MiB
// L3 — HBM FETCH stays ~134MB either way.
__global__ __launch_bounds__(128)
void compress_k_fused(const float* __restrict__ k,
                      const int* __restrict__ cu_seqlens,
                      float* __restrict__ out,
                      float* __restrict__ tail) {
    // Bijective XCD-aware swizzle (m204 form; 4092 = 8*511 + 4, naive form
    // would be non-bijective). Adjacent chunks -> same XCD's L2.
    const int bid = blockIdx.x;
    const int xcd = bid % NXCD;
    const int sub = bid / NXCD;
    const int q8  = TOTAL_CHUNKS / NXCD;          // 511
    const int r8  = TOTAL_CHUNKS % NXCD;          // 4
    const int blk = (xcd < r8 ? xcd * (q8 + 1)
                              : r8 * (q8 + 1) + (xcd - r8) * q8) + sub;

    const int b = blk / CHUNKS_PER_BATCH;
    const int c = blk - b * CHUNKS_PER_BATCH;     // chunk index within batch

    const long start_row = (long)cu_seqlens[b] + (long)c * KSTRIDE;
    const float4* __restrict__ src = (const float4*)(k + start_row * ROW);
    const int t = threadIdx.x;                    // 0..127, owns float4 column t

    // Sum the 32 rows of this chunk. Two 16-row accumulation chains (matches
    // round-0's summation order; keeps the fp dependence chain short).
    float4 h0 = make_float4(0.f, 0.f, 0.f, 0.f);
    float4 h1 = make_float4(0.f, 0.f, 0.f, 0.f);
    #pragma unroll
    for (int i = 0; i < KSTRIDE; ++i) {
        float4 a = src[(long)i * ROW4 + t];
        float4 c2 = src[(long)(KSTRIDE + i) * ROW4 + t];
        h0.x += a.x;  h0.y += a.y;  h0.z += a.z;  h0.w += a.w;
        h1.x += c2.x; h1.y += c2.y; h1.z += c2.z; h1.w += c2.w;
    }

    const float s = 1.0f / (float)KSIZE;
    float4 r = make_float4((h0.x + h1.x) * s,
                           (h0.y + h1.y) * s,
                           (h0.z + h1.z) * s,
                           (h0.w + h1.w) * s);
    ((float4*)(out + (long)blk * ROW))[t] = r;

    // Fused cu_comp tail write (fp32 representation in the flat out buffer).
    if (bid == 0 && t == 0) {
        int run = 0;
        tail[0] = 0.0f;
        #pragma unroll
        for (int i = 0; i < BATCH; ++i) {
            const int len = cu_seqlens[i + 1] - cu_seqlens[i];
            const int n = (len >= KSIZE) ? (len - KSIZE) / KSTRIDE + 1 : 0;
            run += n;
            tail[i + 1] = (float)run;
        }
    }
}

extern "C" void kernel_launch(void* const* d_in, const int* in_sizes, int n_in,
                              void* d_out, int out_size, void* d_ws, size_t ws_size,
                              hipStream_t stream) {
    const float* k          = (const float*)d_in[0];
    const int*   cu_seqlens = (const int*)d_in[1];
    float*       out        = (float*)d_out;
    float*       tail       = out + (long)TOTAL_CHUNKS * ROW;

    compress_k_fused<<<TOTAL_CHUNKS, 128, 0, stream>>>(k, cu_seqlens, out, tail);
}

// Round 3
// 193.031 us; speedup vs baseline: 1.0432x; 1.0432x over previous
//
#include <hip/hip_runtime.h>

// Problem constants (from reference)
#define KSIZE   32
#define KSTRIDE 16
#define HK      4
#define HD      128
#define ROW     (HK * HD)                       // 512 floats per token
#define ROW4    (ROW / 4)                       // 128 float4 per token
#define BATCH   4
#define SEQLEN  16384
#define CHUNKS_PER_BATCH ((SEQLEN - KSIZE) / KSTRIDE + 1)   // 1023
#define TOTAL_CHUNKS     (BATCH * CHUNKS_PER_BATCH)         // 4092

// Sequential-span decomposition: each block owns SPAN contiguous chunks and
// walks them serially, carrying the shared 16-row half-window sum in
// registers. Requested bytes = (4092 + B)*32KB; at B=512 that is 150.9 MB
// (vs 178.8 MB for round-0's G=3, 268 MB for G=1). 512 blocks = exactly
// 2 blocks/CU (no tail imbalance). Evidence from rounds 1-2: time tracks
// requested bytes, not occupancy -- so minimize bytes, keep structure flat
// (no LDS, no sync, no VGPR cap).
#define SPAN 8
#define BLOCKS_PER_BATCH ((CHUNKS_PER_BATCH + SPAN - 1) / SPAN)  // 128
#define TOTAL_BLOCKS     (BATCH * BLOCKS_PER_BATCH)              // 512

// Sum 16 consecutive rows (starting at row0) of column t. Two independent
// accumulation chains; 16 independent loads for the scheduler to hoist.
__device__ __forceinline__ float4 sum16(const float4* __restrict__ src,
                                        int row0, int t) {
    float4 a0 = make_float4(0.f, 0.f, 0.f, 0.f);
    float4 a1 = make_float4(0.f, 0.f, 0.f, 0.f);
    #pragma unroll
    for (int i = 0; i < 8; ++i) {
        float4 u = src[(long)(row0 + 2 * i)     * ROW4 + t];
        float4 v = src[(long)(row0 + 2 * i + 1) * ROW4 + t];
        a0.x += u.x; a0.y += u.y; a0.z += u.z; a0.w += u.w;
        a1.x += v.x; a1.y += v.y; a1.z += v.z; a1.w += v.w;
    }
    a0.x += a1.x; a0.y += a1.y; a0.z += a1.z; a0.w += a1.w;
    return a0;
}

__global__ __launch_bounds__(128)
void compress_k_fused(const float* __restrict__ k,
                      const int* __restrict__ cu_seqlens,
                      float* __restrict__ out,
                      float* __restrict__ tail) {
    const int blk = blockIdx.x;
    const int b   = blk / BLOCKS_PER_BATCH;
    const int cb  = blk - b * BLOCKS_PER_BATCH;
    const int c0  = cb * SPAN;                               // first chunk
    const int gc  = (CHUNKS_PER_BATCH - c0 < SPAN) ? (CHUNKS_PER_BATCH - c0)
                                                   : SPAN;   // 8, or 7 (last)

    const long start_row = (long)cu_seqlens[b] + (long)c0 * KSTRIDE;
    const float4* __restrict__ src = (const float4*)(k + start_row * ROW);
    const int t = threadIdx.x;                               // float4 column

    const float s = 1.0f / (float)KSIZE;
    float* outp = out + (long)(b * CHUNKS_PER_BATCH + c0) * ROW;

    float4 prev = sum16(src, 0, t);

    if (gc == SPAN) {
        // Hot path: fully unrolled so the compiler overlaps next-window
        // loads with current-window adds and the store.
        #pragma unroll
        for (int g = 0; g < SPAN; ++g) {
            float4 cur = sum16(src, (g + 1) * KSTRIDE, t);
            float4 r = make_float4((prev.x + cur.x) * s,
                                   (prev.y + cur.y) * s,
                                   (prev.z + cur.z) * s,
                                   (prev.w + cur.w) * s);
            ((float4*)(outp + (long)g * ROW))[t] = r;
            prev = cur;
        }
    } else {
        for (int g = 0; g < gc; ++g) {
            float4 cur = sum16(src, (g + 1) * KSTRIDE, t);
            float4 r = make_float4((prev.x + cur.x) * s,
                                   (prev.y + cur.y) * s,
                                   (prev.z + cur.z) * s,
                                   (prev.w + cur.w) * s);
            ((float4*)(outp + (long)g * ROW))[t] = r;
            prev = cur;
        }
    }

    // Fused cu_comp tail write (fp32 representation in the flat out buffer).
    if (blk == 0 && t == 0) {
        int run = 0;
        tail[0] = 0.0f;
        #pragma unroll
        for (int i = 0; i < BATCH; ++i) {
            const int len = cu_seqlens[i + 1] - cu_seqlens[i];
            const int n = (len >= KSIZE) ? (len - KSIZE) / KSTRIDE + 1 : 0;
            run += n;
            tail[i + 1] = (float)run;
        }
    }
}

extern "C" void kernel_launch(void* const* d_in, const int* in_sizes, int n_in,
                              void* d_out, int out_size, void* d_ws, size_t ws_size,
                              hipStream_t stream) {
    const float* k          = (const float*)d_in[0];
    const int*   cu_seqlens = (const int*)d_in[1];
    float*       out        = (float*)d_out;
    float*       tail       = out + (long)TOTAL_CHUNKS * ROW;

    compress_k_fused<<<TOTAL_BLOCKS, 128, 0, stream>>>(k, cu_seqlens, out, tail);
}